// Round 1
// baseline (246.247 us; speedup 1.0000x reference)
//
#include <hip/hip_runtime.h>

#define N_TOT 400000
#define NBLK  6250          // N_TOT / 64 voxels per block
#define NELEM (N_TOT * 16)

typedef __attribute__((ext_vector_type(8))) short short8;
typedef __attribute__((ext_vector_type(4))) float f32x4;
typedef __attribute__((ext_vector_type(4))) unsigned short us4;

__device__ __forceinline__ unsigned short f2bf(float x) {
    unsigned int u = __float_as_uint(x);
    u += 0x7FFFu + ((u >> 16) & 1u);       // round-to-nearest-even
    return (unsigned short)(u >> 16);
}

// Build bf16 B-fragments for all 5 layers x 14 k-pairs.
// Fragment layout for mfma_f32_16x16x32_bf16: lane l holds B[k=8*(l>>4)+j][col=l&15].
// k-pair p covers offsets 2p (klocal 0..15) and 2p+1 (klocal 16..31); offset 27 = zero pad.
__global__ __launch_bounds__(64) void wfrag_k(const float* __restrict__ w_in,
                                              const float* __restrict__ wbs,
                                              unsigned short* __restrict__ wfrag) {
    int b = blockIdx.x;            // L*14 + p
    int L = b / 14, p = b % 14;
    int l = threadIdx.x;
    int g = l >> 4, col = l & 15;
    int k = 2 * p + (g >> 1);
    int cib = (g & 1) * 8;
    unsigned short v[8];
#pragma unroll
    for (int j = 0; j < 8; ++j) {
        float w = 0.f;
        if (k < 27) {
            int ci = cib + j;
            w = (L == 0) ? w_in[(k * 16 + ci) * 16 + col]
                         : wbs[(((L - 1) * 27 + k) * 16 + ci) * 16 + col];
        }
        v[j] = f2bf(w);
    }
    unsigned short* dst = wfrag + (size_t)(b * 64 + l) * 8;
#pragma unroll
    for (int j = 0; j < 8; ++j) dst[j] = v[j];
}

__global__ __launch_bounds__(256) void cvt_k(const float* __restrict__ in,
                                             unsigned short* __restrict__ out) {
    int i = (blockIdx.x * 256 + threadIdx.x) * 4;
    f32x4 v = *reinterpret_cast<const f32x4*>(in + i);
    us4 o = { f2bf(v[0]), f2bf(v[1]), f2bf(v[2]), f2bf(v[3]) };
    *reinterpret_cast<us4*>(out + i) = o;
}

// Gather-MFMA submanifold conv: 1 wave = 16 voxels, 4 waves/block.
// All 27 offsets' weights live in 14 B-fragments (56 VGPRs). Always-run bodies
// (masked-zero A rows for invalid neighbors) keep control flow wave-uniform and
// let all 14 gathers issue ahead of the MFMA chain.
__global__ __launch_bounds__(256) void conv_k(const unsigned short* __restrict__ feats,
                                              const int* __restrict__ nbr,
                                              const unsigned short* __restrict__ wfrag,
                                              float* __restrict__ out,
                                              float* __restrict__ partials) {
    const int lane = threadIdx.x & 63;
    const int wv   = threadIdx.x >> 6;
    const int v0   = (blockIdx.x * 4 + wv) * 16;
    const int g    = lane >> 4;
    const int rc   = lane & 15;        // A-row / B-col
    const int half = (g & 1) * 8;      // which 8 input channels this lane loads
    const int ksel = g >> 1;           // which offset of the pair

    short8 bfr[14];
#pragma unroll
    for (int p = 0; p < 14; ++p)
        bfr[p] = *reinterpret_cast<const short8*>(wfrag + (size_t)(p * 64 + lane) * 8);

    int idxs[14];
#pragma unroll
    for (int p = 0; p < 14; ++p) {
        int k = 2 * p + ksel;
        idxs[p] = (k < 27) ? nbr[k * N_TOT + v0 + rc] : -1;
    }

    f32x4 acc = {0.f, 0.f, 0.f, 0.f};
#pragma unroll
    for (int p = 0; p < 14; ++p) {
        int idx = idxs[p];
        bool valid = idx >= 0;
        int ci = valid ? idx : 0;
        short8 a = *reinterpret_cast<const short8*>(feats + (size_t)ci * 16 + half);
        if (!valid) { short8 z = {0, 0, 0, 0, 0, 0, 0, 0}; a = z; }
        acc = __builtin_amdgcn_mfma_f32_16x16x32_bf16(a, bfr[p], acc, 0, 0, 0);
    }

    // C/D layout: col = lane&15, row = (lane>>4)*4 + reg  [m89/m91 verified]
#pragma unroll
    for (int i = 0; i < 4; ++i)
        out[(size_t)(v0 + g * 4 + i) * 16 + rc] = acc[i];

    // deterministic BN partials: per-channel sum & sumsq over this block's 64 voxels
    float s = acc[0] + acc[1] + acc[2] + acc[3];
    float q = acc[0] * acc[0] + acc[1] * acc[1] + acc[2] * acc[2] + acc[3] * acc[3];
    s += __shfl_xor(s, 16);  s += __shfl_xor(s, 32);
    q += __shfl_xor(q, 16);  q += __shfl_xor(q, 32);

    __shared__ float red[128];
    if (lane < 16) {
        red[wv * 32 + rc]      = s;
        red[wv * 32 + 16 + rc] = q;
    }
    __syncthreads();
    if (threadIdx.x < 32) {
        float v = red[threadIdx.x] + red[32 + threadIdx.x] +
                  red[64 + threadIdx.x] + red[96 + threadIdx.x];
        partials[(size_t)threadIdx.x * NBLK + blockIdx.x] = v;  // [32][NBLK] layout
    }
}

__global__ __launch_bounds__(256) void reduce_k(const float* __restrict__ partials,
                                                float* __restrict__ S) {
    int c = blockIdx.x;  // 0..31 (16 sums, 16 sumsqs)
    float s = 0.f;
    for (int i = threadIdx.x; i < NBLK; i += 256) s += partials[(size_t)c * NBLK + i];
    __shared__ float red[256];
    red[threadIdx.x] = s;
    __syncthreads();
#pragma unroll
    for (int off = 128; off > 0; off >>= 1) {
        if (threadIdx.x < off) red[threadIdx.x] += red[threadIdx.x + off];
        __syncthreads();
    }
    if (threadIdx.x == 0) S[c] = red[0];
}

// BN finalize arithmetic fused in; optional residual add, ReLU, f32 and/or bf16 outputs.
// NOTE: no __restrict__ on t/resid/f32out — they intentionally alias in some layers.
__global__ __launch_bounds__(256) void apply_k(const float* t,
                                               const float* __restrict__ S,
                                               const float* __restrict__ gamma,
                                               const float* __restrict__ beta,
                                               const float* resid,
                                               float* f32out,
                                               unsigned short* bfout) {
    int i = (blockIdx.x * 256 + threadIdx.x) * 4;
    int c = i & 12;
    f32x4 t4 = *reinterpret_cast<const f32x4*>(t + i);
    f32x4 r4 = {0.f, 0.f, 0.f, 0.f};
    if (resid) r4 = *reinterpret_cast<const f32x4*>(resid + i);
    const float inv = 1.0f / (float)N_TOT;
    f32x4 val;
#pragma unroll
    for (int j = 0; j < 4; ++j) {
        float m   = S[c + j] * inv;
        float var = S[16 + c + j] * inv - m * m;
        float sc  = gamma[c + j] * rsqrtf(var + 1e-3f);
        float sh  = beta[c + j] - m * sc;
        val[j] = fmaxf(t4[j] * sc + sh + r4[j], 0.f);
    }
    if (f32out) *reinterpret_cast<f32x4*>(f32out + i) = val;
    if (bfout) {
        us4 o = { f2bf(val[0]), f2bf(val[1]), f2bf(val[2]), f2bf(val[3]) };
        *reinterpret_cast<us4*>(bfout + i) = o;
    }
}

extern "C" void kernel_launch(void* const* d_in, const int* in_sizes, int n_in,
                              void* d_out, int out_size, void* d_ws, size_t ws_size,
                              hipStream_t stream) {
    const float* vf   = (const float*)d_in[0];
    const int*   nbr  = (const int*)  d_in[1];
    const float* w_in = (const float*)d_in[2];
    const float* g_in = (const float*)d_in[3];
    const float* b_in = (const float*)d_in[4];
    const float* wbs  = (const float*)d_in[5];
    const float* gs   = (const float*)d_in[6];
    const float* bs   = (const float*)d_in[7];
    float* out = (float*)d_out;

    char* ws = (char*)d_ws;
    size_t off = 0;
    auto alloc = [&](size_t b) { char* p = ws + off; off += (b + 255) & ~(size_t)255; return p; };
    unsigned short* wfrag = (unsigned short*)alloc((size_t)5 * 14 * 64 * 8 * 2);
    unsigned short* xb    = (unsigned short*)alloc((size_t)NELEM * 2);  // bf16 features (x)
    unsigned short* ob    = (unsigned short*)alloc((size_t)NELEM * 2);  // bf16 features (o)
    float*          xf    = (float*)alloc((size_t)NELEM * 4);           // f32 residual copy
    float*          part  = (float*)alloc((size_t)32 * NBLK * 4);
    float*          S     = (float*)alloc(32 * 4);

    const int FR = 14 * 64 * 8;  // ushorts per layer of wfrag

    wfrag_k<<<70, 64, 0, stream>>>(w_in, wbs, wfrag);
    cvt_k<<<6250, 256, 0, stream>>>(vf, xb);

    // L0: x0 = relu(bn(conv(vf)))                 -> xb (bf16) + xf (f32)
    conv_k<<<NBLK, 256, 0, stream>>>(xb, nbr, wfrag, out, part);
    reduce_k<<<32, 256, 0, stream>>>(part, S);
    apply_k<<<6250, 256, 0, stream>>>(out, S, g_in, b_in, nullptr, xf, xb);

    // L1: o = relu(bn(conv(x0)))                  -> ob
    conv_k<<<NBLK, 256, 0, stream>>>(xb, nbr, wfrag + FR, out, part);
    reduce_k<<<32, 256, 0, stream>>>(part, S);
    apply_k<<<6250, 256, 0, stream>>>(out, S, gs + 0, bs + 0, nullptr, nullptr, ob);

    // L2: x1 = relu(bn(conv(o)) + x0)             -> xb + xf (in place)
    conv_k<<<NBLK, 256, 0, stream>>>(ob, nbr, wfrag + 2 * FR, out, part);
    reduce_k<<<32, 256, 0, stream>>>(part, S);
    apply_k<<<6250, 256, 0, stream>>>(out, S, gs + 16, bs + 16, xf, xf, xb);

    // L3: o = relu(bn(conv(x1)))                  -> ob
    conv_k<<<NBLK, 256, 0, stream>>>(xb, nbr, wfrag + 3 * FR, out, part);
    reduce_k<<<32, 256, 0, stream>>>(part, S);
    apply_k<<<6250, 256, 0, stream>>>(out, S, gs + 32, bs + 32, nullptr, nullptr, ob);

    // L4: out = relu(bn(conv(o)) + x1)            -> d_out (f32, in place)
    conv_k<<<NBLK, 256, 0, stream>>>(ob, nbr, wfrag + 4 * FR, out, part);
    reduce_k<<<32, 256, 0, stream>>>(part, S);
    apply_k<<<6250, 256, 0, stream>>>(out, S, gs + 48, bs + 48, xf, out, nullptr);
}